// Round 5
// baseline (547.663 us; speedup 1.0000x reference)
//
#include <hip/hip_runtime.h>

#define N_NODES 100000
#define N_EDGES 1600000
#define D 128
#define DE 32
#define SCAN_CHUNK 1024
#define N_CHUNKS ((N_NODES + SCAN_CHUNK - 1) / SCAN_CHUNK)  // 98

// NOTE on eps: reference divides by sqrt(deg_in*deg_out)+1e-10 with both
// degrees >= 1, so the +1e-10 is a 1e-10 relative perturbation — far below
// f32 rounding. We factor w = ew * rsqrt(di) * rsqrt(do).

// ---------------------------------------------------------------------------
// K1: zero deg replicas + cursor (contiguous 5N region).
__global__ __launch_bounds__(256) void init_kernel(int* __restrict__ z) {
  int idx = blockIdx.x * 256 + threadIdx.x;
  if (idx < 5 * N_NODES) z[idx] = 0;
}

// ---------------------------------------------------------------------------
// K2: per-edge: deg_in replica atomic + cursor position atomic. 2 edges/thr.
__global__ __launch_bounds__(256) void pos_kernel(
    const int4* __restrict__ el2, const float2* __restrict__ ew2,
    float* __restrict__ deg4, int* __restrict__ cursor,
    int2* __restrict__ pos2) {
  int i = blockIdx.x * 256 + threadIdx.x;  // edge-pair index
  if (i >= N_EDGES / 2) return;
  int4 e = el2[i];
  float2 w = ew2[i];
  int r = (threadIdx.x & 3) * N_NODES;
  atomicAdd(&deg4[r + e.x], w.x);
  atomicAdd(&deg4[r + e.z], w.y);
  int2 p;
  p.x = atomicAdd(&cursor[e.y], 1);
  p.y = atomicAdd(&cursor[e.w], 1);
  pos2[i] = p;
}

// ---------------------------------------------------------------------------
// K3a: per-1024-chunk exclusive scan of counts(=cursor) -> partial, totals;
// also folds the deg replica reduction into rdi = rsqrt(1 + sum).
__global__ __launch_bounds__(256) void scan1_kernel(
    const int* __restrict__ counts, const float* __restrict__ deg4,
    int* __restrict__ partial, int* __restrict__ blocksum,
    float* __restrict__ rdi) {
  __shared__ int lds[256];
  int t = threadIdx.x;
  int base = blockIdx.x * SCAN_CHUNK + t * 4;
  int c[4];
  int s = 0;
#pragma unroll
  for (int k = 0; k < 4; k++) {
    c[k] = (base + k < N_NODES) ? counts[base + k] : 0;
    s += c[k];
  }
  lds[t] = s;
  __syncthreads();
  for (int off = 1; off < 256; off <<= 1) {
    int tmp = (t >= off) ? lds[t - off] : 0;
    __syncthreads();
    lds[t] += tmp;
    __syncthreads();
  }
  int run = lds[t] - s;
#pragma unroll
  for (int k = 0; k < 4; k++) {
    int v = base + k;
    if (v < N_NODES) {
      partial[v] = run;
      rdi[v] = rsqrtf(1.f + deg4[v] + deg4[N_NODES + v] +
                      deg4[2 * N_NODES + v] + deg4[3 * N_NODES + v]);
    }
    run += c[k];
  }
  if (t == 255) blocksum[blockIdx.x] = lds[255];
}

// ---------------------------------------------------------------------------
// K3b: exclusive scan of the 98 chunk totals.
__global__ __launch_bounds__(128) void scan2_kernel(
    const int* __restrict__ blocksum, int* __restrict__ blockoff) {
  __shared__ int lds[128];
  int t = threadIdx.x;
  int v = (t < N_CHUNKS) ? blocksum[t] : 0;
  lds[t] = v;
  __syncthreads();
  for (int off = 1; off < 128; off <<= 1) {
    int tmp = (t >= off) ? lds[t - off] : 0;
    __syncthreads();
    lds[t] += tmp;
    __syncthreads();
  }
  if (t < N_CHUNKS) blockoff[t] = lds[t] - v;
}

// ---------------------------------------------------------------------------
// K4: place 16B AoS records {src, eid, ew, 0} at start[dst]+pos. No atomics.
__global__ __launch_bounds__(256) void place_kernel(
    const int4* __restrict__ el2, const float2* __restrict__ ew2,
    const int2* __restrict__ pos2, const int* __restrict__ partial,
    const int* __restrict__ blockoff, int4* __restrict__ rec) {
  int i = blockIdx.x * 256 + threadIdx.x;  // edge-pair index
  if (i >= N_EDGES / 2) return;
  int4 e = el2[i];
  float2 w = ew2[i];
  int2 p = pos2[i];
  int4 rA, rB;
  rA.x = e.x; rA.y = 2 * i;     rA.z = __float_as_int(w.x); rA.w = 0;
  rB.x = e.z; rB.y = 2 * i + 1; rB.z = __float_as_int(w.y); rB.w = 0;
  rec[partial[e.y] + blockoff[e.y >> 10] + p.x] = rA;
  rec[partial[e.w] + blockoff[e.w >> 10] + p.y] = rB;
}

// ---------------------------------------------------------------------------
// K5: one wave per dst node.
//  pass1: dsum = sum raw ew  -> rdo = rsqrt(1+dsum)
//  pass2: per-lane w = ew*rdi[src]*rdo; shfl-broadcast; accumulate
//         sum(w*x[src]), sum(w*ef), sum(w). Plain stores, no atomics.
__global__ __launch_bounds__(256) void gather_kernel(
    const float* __restrict__ x, const float* __restrict__ ef,
    const int* __restrict__ partial, const int* __restrict__ blockoff,
    const int* __restrict__ counts, const int4* __restrict__ rec,
    const float* __restrict__ rdi, float* __restrict__ acc,
    float* __restrict__ g, float* __restrict__ wsum,
    float* __restrict__ rdo_arr) {
  int wid = threadIdx.x >> 6;
  int lane = threadIdx.x & 63;
  int v = blockIdx.x * 4 + wid;
  if (v >= N_NODES) return;
  int start = partial[v] + blockoff[v >> 10];
  int cnt = counts[v];

  // pass 1: raw weighted in-degree of v
  float dsum = 0.f;
  for (int p = lane; p < cnt; p += 64)
    dsum += __int_as_float(rec[start + p].z);
#pragma unroll
  for (int off = 32; off; off >>= 1) dsum += __shfl_xor(dsum, off);
  float rdo = rsqrtf(1.f + dsum);

  float a0 = 0.f, a1 = 0.f, b0 = 0.f, b1 = 0.f, ga = 0.f, wsv = 0.f;
  for (int base = 0; base < cnt; base += 64) {
    int nb = cnt - base;
    if (nb > 64) nb = 64;
    int s_l = 0, e_l = 0;
    float w_l = 0.f;
    if (lane < nb) {
      int4 r = rec[start + base + lane];
      s_l = r.x;
      e_l = r.y;
      w_l = __int_as_float(r.z) * rdi[r.x] * rdo;
      wsv += w_l;
    }
    int i = 0;
    for (; i + 2 <= nb; i += 2) {
      int sA = __shfl(s_l, i), sB = __shfl(s_l, i + 1);
      float wA = __shfl(w_l, i), wB = __shfl(w_l, i + 1);
      int eA = __shfl(e_l, i), eB = __shfl(e_l, i + 1);
      const float* xA = x + (size_t)sA * D;
      const float* xB = x + (size_t)sB * D;
      float xa0 = xA[lane], xa1 = xA[lane + 64];
      float xb0 = xB[lane], xb1 = xB[lane + 64];
      float we = (lane < 32) ? wA : wB;
      int ee = (lane < 32) ? eA : eB;
      float efv = ef[(size_t)ee * DE + (lane & 31)];
      a0 = fmaf(wA, xa0, a0);
      a1 = fmaf(wA, xa1, a1);
      b0 = fmaf(wB, xb0, b0);
      b1 = fmaf(wB, xb1, b1);
      ga = fmaf(we, efv, ga);
    }
    if (i < nb) {
      int sA = __shfl(s_l, i);
      float wA = __shfl(w_l, i);
      int eA = __shfl(e_l, i);
      const float* xA = x + (size_t)sA * D;
      a0 = fmaf(wA, xA[lane], a0);
      a1 = fmaf(wA, xA[lane + 64], a1);
      if (lane < DE) ga = fmaf(wA, ef[(size_t)eA * DE + lane], ga);
    }
  }
  a0 += b0;
  a1 += b1;
#pragma unroll
  for (int off = 32; off; off >>= 1) wsv += __shfl_xor(wsv, off);
  float gaHi = __shfl(ga, (lane + 32) & 63);
  float* ad = acc + (size_t)v * D;
  ad[lane] = a0;
  ad[lane + 64] = a1;
  if (lane < DE) g[v * DE + lane] = ga + gaHi;
  if (lane == 0) {
    wsum[v] = wsv;
    rdo_arr[v] = rdo;
  }
}

// ---------------------------------------------------------------------------
// K6a: in-place row-local update (wave per node):
//   out[v] = out[v] + wself*x[v] + g[v] @ W_edge^T + wsum[v]*b_edge
// W_edge staged in LDS [128][36] (16B-aligned rows, b128 reads at wave floor).
__global__ __launch_bounds__(256) void upd_kernel(
    const float* __restrict__ x, const float* __restrict__ rdi,
    const float* __restrict__ rdo_arr, const float* __restrict__ wsum,
    const float* __restrict__ g, const float* __restrict__ W_edge,
    const float* __restrict__ b_edge, float* __restrict__ out) {
  __shared__ __align__(16) float we[128 * 36];
  int t = threadIdx.x;
#pragma unroll
  for (int i = 0; i < 4; ++i) {  // 1024 float4 / 256 threads
    int f = t + i * 256;
    int r = f >> 3, kq = f & 7;
    *(float4*)&we[r * 36 + 4 * kq] = *(const float4*)&W_edge[r * DE + 4 * kq];
  }
  __syncthreads();

  int wid = t >> 6, lane = t & 63;
  int v = blockIdx.x * 4 + wid;
  if (v >= N_NODES) return;
  float wself = rdi[v] * rdo_arr[v];
  float ws = wsum[v];
  float gk = g[v * DE + (lane & 31)];
  size_t ro = (size_t)v * D;
  float s0 = out[ro + lane] + wself * x[ro + lane] + ws * b_edge[lane];
  float s1 = out[ro + lane + 64] + wself * x[ro + lane + 64] +
             ws * b_edge[lane + 64];
#pragma unroll
  for (int kq = 0; kq < 8; ++kq) {
    float4 w0 = *(const float4*)&we[lane * 36 + 4 * kq];
    float4 w1 = *(const float4*)&we[(lane + 64) * 36 + 4 * kq];
    float g0 = __shfl(gk, 4 * kq);
    float g1 = __shfl(gk, 4 * kq + 1);
    float g2 = __shfl(gk, 4 * kq + 2);
    float g3 = __shfl(gk, 4 * kq + 3);
    s0 += g0 * w0.x + g1 * w0.y + g2 * w0.z + g3 * w0.w;
    s1 += g0 * w1.x + g1 * w1.y + g2 * w1.z + g3 * w1.w;
  }
  out[ro + lane] = s0;
  out[ro + lane + 64] = s1;
}

// ---------------------------------------------------------------------------
// K6b: in-place per-128-row-tile SGEMM: out = relu(out @ W_lin^T + b_lin).
// BM=128, BN=128, BK=32; 8x8 thread tile split (4+4)x(4+4).
// LDS: stride-32 rows with float4 XOR swizzle (4kq ^ 4*((row>>2)&7)):
// A-reads broadcast, B-reads 2-way, staging at the b128 wave floor.
__global__ __launch_bounds__(256) void gemm2_kernel(
    const float* __restrict__ W_lin, const float* __restrict__ b_lin,
    float* __restrict__ out) {
  __shared__ __align__(16) float xs[128 * 32];
  __shared__ __align__(16) float wl[128 * 32];
  int t = threadIdx.x;
  int tn = t & 15, tm = t >> 4;
  int m0 = 4 * tm, n0 = 4 * tn;
  int vbase = blockIdx.x * 128;
  float acc[8][8] = {};  // [mi][nj]; mi>=4 -> row m0+64+mi-4, nj>=4 -> col+64

  for (int ks = 0; ks < D; ks += 32) {
    __syncthreads();
#pragma unroll
    for (int i = 0; i < 4; ++i) {  // 1024 float4 / 256 threads, each array
      int f = t + i * 256;
      int r = f >> 3, kq = f & 7;
      int sw = (4 * kq) ^ (4 * ((r >> 2) & 7));
      float4 xv = make_float4(0.f, 0.f, 0.f, 0.f);
      if (vbase + r < N_NODES)
        xv = *(const float4*)&out[(size_t)(vbase + r) * D + ks + 4 * kq];
      *(float4*)&xs[r * 32 + sw] = xv;
      *(float4*)&wl[r * 32 + sw] = *(const float4*)&W_lin[r * D + ks + 4 * kq];
    }
    __syncthreads();
#pragma unroll
    for (int kq = 0; kq < 8; ++kq) {
      int sa = (4 * kq) ^ (4 * (tm & 7));
      int sb = (4 * kq) ^ (4 * (tn & 7));
      float4 a[8], b[8];
#pragma unroll
      for (int i = 0; i < 4; ++i) {
        a[i] = *(const float4*)&xs[(m0 + i) * 32 + sa];
        a[4 + i] = *(const float4*)&xs[(m0 + 64 + i) * 32 + sa];
        b[i] = *(const float4*)&wl[(n0 + i) * 32 + sb];
        b[4 + i] = *(const float4*)&wl[(n0 + 64 + i) * 32 + sb];
      }
#pragma unroll
      for (int i = 0; i < 8; ++i)
#pragma unroll
        for (int j = 0; j < 8; ++j) {
          acc[i][j] += a[i].x * b[j].x + a[i].y * b[j].y + a[i].z * b[j].z +
                       a[i].w * b[j].w;
        }
    }
  }

  float bl[8];
#pragma unroll
  for (int j = 0; j < 4; ++j) {
    bl[j] = b_lin[n0 + j];
    bl[4 + j] = b_lin[n0 + 64 + j];
  }
#pragma unroll
  for (int i = 0; i < 8; ++i) {
    int m = vbase + m0 + (i < 4 ? i : 64 + i - 4);
    if (m >= N_NODES) continue;
    float4 o0, o1;
    o0.x = fmaxf(acc[i][0] + bl[0], 0.f);
    o0.y = fmaxf(acc[i][1] + bl[1], 0.f);
    o0.z = fmaxf(acc[i][2] + bl[2], 0.f);
    o0.w = fmaxf(acc[i][3] + bl[3], 0.f);
    o1.x = fmaxf(acc[i][4] + bl[4], 0.f);
    o1.y = fmaxf(acc[i][5] + bl[5], 0.f);
    o1.z = fmaxf(acc[i][6] + bl[6], 0.f);
    o1.w = fmaxf(acc[i][7] + bl[7], 0.f);
    *(float4*)&out[(size_t)m * D + n0] = o0;
    *(float4*)&out[(size_t)m * D + n0 + 64] = o1;
  }
}

// ---------------------------------------------------------------------------
extern "C" void kernel_launch(void* const* d_in, const int* in_sizes, int n_in,
                              void* d_out, int out_size, void* d_ws,
                              size_t ws_size, hipStream_t stream) {
  const float* x      = (const float*)d_in[0];
  const int*   el     = (const int*)d_in[1];
  const float* ew     = (const float*)d_in[2];
  const float* ef     = (const float*)d_in[3];
  const float* W_lin  = (const float*)d_in[4];
  const float* b_lin  = (const float*)d_in[5];
  const float* W_edge = (const float*)d_in[6];
  const float* b_edge = (const float*)d_in[7];

  float* acc = (float*)d_out;  // gather writes; upd/gemm2 transform in place

  // workspace layout (~48 MB), rec first for 16B alignment
  int4* rec      = (int4*)d_ws;                         // E x 16B
  int*  pos      = (int*)(rec + N_EDGES);               // E
  float* deg4    = (float*)(pos + N_EDGES);             // 4N (zeroed w/ cursor)
  int*  cursor   = (int*)(deg4 + 4 * N_NODES);          // N (== counts after K2)
  int*  partial  = cursor + N_NODES;                    // N
  int*  blocksum = partial + N_NODES;                   // 128
  int*  blockoff = blocksum + 128;                      // 128
  float* rdi     = (float*)(blockoff + 128);            // N
  float* rdo     = rdi + N_NODES;                       // N
  float* wsum    = rdo + N_NODES;                       // N
  float* g       = wsum + N_NODES;                      // N*32

  hipLaunchKernelGGL(init_kernel, dim3((5 * N_NODES + 255) / 256), dim3(256),
                     0, stream, (int*)deg4);
  hipLaunchKernelGGL(pos_kernel, dim3((N_EDGES / 2 + 255) / 256), dim3(256), 0,
                     stream, (const int4*)el, (const float2*)ew, deg4, cursor,
                     (int2*)pos);
  hipLaunchKernelGGL(scan1_kernel, dim3(N_CHUNKS), dim3(256), 0, stream,
                     cursor, deg4, partial, blocksum, rdi);
  hipLaunchKernelGGL(scan2_kernel, dim3(1), dim3(128), 0, stream, blocksum,
                     blockoff);
  hipLaunchKernelGGL(place_kernel, dim3((N_EDGES / 2 + 255) / 256), dim3(256),
                     0, stream, (const int4*)el, (const float2*)ew,
                     (const int2*)pos, partial, blockoff, rec);
  hipLaunchKernelGGL(gather_kernel, dim3((N_NODES + 3) / 4), dim3(256), 0,
                     stream, x, ef, partial, blockoff, cursor, rec, rdi, acc, g,
                     wsum, rdo);
  hipLaunchKernelGGL(upd_kernel, dim3((N_NODES + 3) / 4), dim3(256), 0, stream,
                     x, rdi, rdo, wsum, g, W_edge, b_edge, acc);
  hipLaunchKernelGGL(gemm2_kernel, dim3((N_NODES + 127) / 128), dim3(256), 0,
                     stream, W_lin, b_lin, acc);
}